// Round 6
// baseline (485.590 us; speedup 1.0000x reference)
//
#include <hip/hip_runtime.h>
#include <stdint.h>

typedef __bf16 bf16;
typedef __bf16 bfx8 __attribute__((ext_vector_type(8)));
typedef float floatx4 __attribute__((ext_vector_type(4)));

#define B_ 2
#define S_ 2048
#define DIM_ 2048
#define H_ 16
#define DK_ 128
#define DR_ 64
#define DC_ 512
#define DCP_ 1024
#define DV_ 128
#define DQK_ 192

#define MASK_VAL (-30000.0f)

// ----------------------------------------------------------------------------
// Batched transpose + downcast: in f32 [Hb][K][N] -> out bf16 [Hb][N][K]
// ----------------------------------------------------------------------------
__global__ void k_transpose(const float* __restrict__ in, bf16* __restrict__ out,
                            int K, int N) {
    __shared__ float tile[32][33];
    int h = blockIdx.z;
    int n0 = blockIdx.x * 32, k0 = blockIdx.y * 32;
    const float* ip = in + (size_t)h * K * N;
    bf16* op = out + (size_t)h * K * N;
    int tx = threadIdx.x & 31, ty = threadIdx.x >> 5;
#pragma unroll
    for (int i = 0; i < 32; i += 8)
        tile[ty + i][tx] = ip[(size_t)(k0 + ty + i) * N + (n0 + tx)];
    __syncthreads();
#pragma unroll
    for (int i = 0; i < 32; i += 8)
        op[(size_t)(n0 + ty + i) * K + (k0 + tx)] = (bf16)tile[tx][ty + i];
}

// ----------------------------------------------------------------------------
// 8-element row loaders (convert to bf16 if source is f32)
// ----------------------------------------------------------------------------
__device__ __forceinline__ bfx8 load8(const bf16* p) { return *(const bfx8*)p; }
__device__ __forceinline__ bfx8 load8(const float* p) {
    float4 a = *(const float4*)p;
    float4 b = *(const float4*)(p + 4);
    bfx8 r;
    r[0] = (bf16)a.x; r[1] = (bf16)a.y; r[2] = (bf16)a.z; r[3] = (bf16)a.w;
    r[4] = (bf16)b.x; r[5] = (bf16)b.y; r[6] = (bf16)b.z; r[7] = (bf16)b.w;
    return r;
}

// ----------------------------------------------------------------------------
// GEMM core: C[128x128] tile of A[M,K] @ Bt[N,K]^T, f32 acc.
// ----------------------------------------------------------------------------
#define LSTR 40

template <typename TA>
__device__ __forceinline__ void gemm_core(const TA* __restrict__ A,
                                          const bf16* __restrict__ Bt,
                                          int K, int rowlimB,
                                          floatx4 acc[4][4],
                                          bf16* A_lds, bf16* B_lds) {
    int tid = threadIdx.x;
    int wave = tid >> 6, lane = tid & 63;
    int l15 = lane & 15, quad = lane >> 4;
    int wm = (wave & 1) * 64, wn = (wave >> 1) * 64;
    int r0 = tid >> 2;
    int c0 = (tid & 3) * 8;
    int rb0 = r0 <= rowlimB ? r0 : rowlimB;
    int rb1 = (r0 + 64) <= rowlimB ? (r0 + 64) : rowlimB;
    for (int k0 = 0; k0 < K; k0 += 32) {
        bfx8 ra0 = load8(A + (size_t)r0 * K + k0 + c0);
        bfx8 ra1 = load8(A + (size_t)(r0 + 64) * K + k0 + c0);
        bfx8 vb0 = load8(Bt + (size_t)rb0 * K + k0 + c0);
        bfx8 vb1 = load8(Bt + (size_t)rb1 * K + k0 + c0);
        __syncthreads();
        *(bfx8*)(A_lds + r0 * LSTR + c0) = ra0;
        *(bfx8*)(A_lds + (r0 + 64) * LSTR + c0) = ra1;
        *(bfx8*)(B_lds + r0 * LSTR + c0) = vb0;
        *(bfx8*)(B_lds + (r0 + 64) * LSTR + c0) = vb1;
        __syncthreads();
        bfx8 a[4], b[4];
#pragma unroll
        for (int t = 0; t < 4; ++t)
            a[t] = *(const bfx8*)(A_lds + (wm + t * 16 + l15) * LSTR + quad * 8);
#pragma unroll
        for (int t = 0; t < 4; ++t)
            b[t] = *(const bfx8*)(B_lds + (wn + t * 16 + l15) * LSTR + quad * 8);
#pragma unroll
        for (int mt = 0; mt < 4; ++mt)
#pragma unroll
            for (int nt = 0; nt < 4; ++nt)
                acc[mt][nt] = __builtin_amdgcn_mfma_f32_16x16x32_bf16(
                    a[mt], b[nt], acc[mt][nt], 0, 0, 0);
    }
}

// G1: x(f32) -> {c, cp, k_r} (bf16).  grid (13, 32)
__global__ __launch_bounds__(256, 2) void k_gemm1(
    const float* __restrict__ x, const bf16* __restrict__ Wt_c,
    const bf16* __restrict__ Wt_cp, const bf16* __restrict__ Wt_kr,
    bf16* __restrict__ c_ws, bf16* __restrict__ cp_ws, bf16* __restrict__ kr_ws) {
    __shared__ __attribute__((aligned(16))) bf16 A_lds[128 * LSTR];
    __shared__ __attribute__((aligned(16))) bf16 B_lds[128 * LSTR];
    int bx = blockIdx.x, by = blockIdx.y;
    const bf16* Bt; bf16* outp; int ldc, col0, rowlim;
    if (bx < 4)       { Bt = Wt_c  + (size_t)bx * 128 * DIM_;       outp = c_ws;  ldc = DC_;  col0 = bx * 128;       rowlim = 127; }
    else if (bx < 12) { Bt = Wt_cp + (size_t)(bx - 4) * 128 * DIM_; outp = cp_ws; ldc = DCP_; col0 = (bx - 4) * 128; rowlim = 127; }
    else              { Bt = Wt_kr;                                  outp = kr_ws; ldc = DR_;  col0 = 0;              rowlim = 63;  }
    floatx4 acc[4][4];
#pragma unroll
    for (int i = 0; i < 4; ++i)
#pragma unroll
        for (int j = 0; j < 4; ++j) acc[i][j] = (floatx4){0.f, 0.f, 0.f, 0.f};
    gemm_core(x + (size_t)by * 128 * DIM_, Bt, DIM_, rowlim, acc, A_lds, B_lds);
    int tid = threadIdx.x, wave = tid >> 6, lane = tid & 63;
    int l15 = lane & 15, quad = lane >> 4;
    int wm = (wave & 1) * 64, wn = (wave >> 1) * 64;
#pragma unroll
    for (int mt = 0; mt < 4; ++mt)
#pragma unroll
        for (int nt = 0; nt < 4; ++nt) {
            int n = wn + nt * 16 + l15;
            if (n > rowlim) continue;
#pragma unroll
            for (int r = 0; r < 4; ++r) {
                int m = by * 128 + wm + mt * 16 + quad * 4 + r;
                outp[(size_t)m * ldc + col0 + n] = (bf16)acc[mt][nt][r];
            }
        }
}

// G2: cp -> q (q_c cols 0..127, q_r cols 128..191), per head. grid (2, 32, 16)
__global__ __launch_bounds__(256, 2) void k_gemm2(
    const bf16* __restrict__ cp_ws, const bf16* __restrict__ Wt_qc,
    const bf16* __restrict__ Wt_qr, bf16* __restrict__ q_ws) {
    __shared__ __attribute__((aligned(16))) bf16 A_lds[128 * LSTR];
    __shared__ __attribute__((aligned(16))) bf16 B_lds[128 * LSTR];
    int bx = blockIdx.x, by = blockIdx.y, h = blockIdx.z;
    const bf16* Bt; int col0, rowlim;
    if (bx == 0) { Bt = Wt_qc + (size_t)h * DK_ * DCP_; col0 = 0;   rowlim = 127; }
    else         { Bt = Wt_qr + (size_t)h * DR_ * DCP_; col0 = 128; rowlim = 63;  }
    floatx4 acc[4][4];
#pragma unroll
    for (int i = 0; i < 4; ++i)
#pragma unroll
        for (int j = 0; j < 4; ++j) acc[i][j] = (floatx4){0.f, 0.f, 0.f, 0.f};
    gemm_core(cp_ws + (size_t)by * 128 * DCP_, Bt, DCP_, rowlim, acc, A_lds, B_lds);
    int tid = threadIdx.x, wave = tid >> 6, lane = tid & 63;
    int l15 = lane & 15, quad = lane >> 4;
    int wm = (wave & 1) * 64, wn = (wave >> 1) * 64;
#pragma unroll
    for (int mt = 0; mt < 4; ++mt)
#pragma unroll
        for (int nt = 0; nt < 4; ++nt) {
            int n = wn + nt * 16 + l15;
            if (n > rowlim) continue;
#pragma unroll
            for (int r = 0; r < 4; ++r) {
                int m = by * 128 + wm + mt * 16 + quad * 4 + r;
                int b = m >> 11, s = m & 2047;
                q_ws[(((size_t)b * H_ + h) * S_ + s) * DQK_ + col0 + n] = (bf16)acc[mt][nt][r];
            }
        }
}

// G3: c -> {k_c [B,H,S,128], v^T [B,H,128,S]}, per head. grid (2, 32, 16)
__global__ __launch_bounds__(256, 2) void k_gemm3(
    const bf16* __restrict__ c_ws, const bf16* __restrict__ Wt_kc,
    const bf16* __restrict__ Wt_v, bf16* __restrict__ kc_ws, bf16* __restrict__ vt_ws) {
    __shared__ __attribute__((aligned(16))) bf16 A_lds[128 * LSTR];
    __shared__ __attribute__((aligned(16))) bf16 B_lds[128 * LSTR];
    int bx = blockIdx.x, by = blockIdx.y, h = blockIdx.z;
    const bf16* Bt = (bx == 0) ? (Wt_kc + (size_t)h * DK_ * DC_)
                               : (Wt_v  + (size_t)h * DV_ * DC_);
    floatx4 acc[4][4];
#pragma unroll
    for (int i = 0; i < 4; ++i)
#pragma unroll
        for (int j = 0; j < 4; ++j) acc[i][j] = (floatx4){0.f, 0.f, 0.f, 0.f};
    gemm_core(c_ws + (size_t)by * 128 * DC_, Bt, DC_, 127, acc, A_lds, B_lds);
    int tid = threadIdx.x, wave = tid >> 6, lane = tid & 63;
    int l15 = lane & 15, quad = lane >> 4;
    int wm = (wave & 1) * 64, wn = (wave >> 1) * 64;
#pragma unroll
    for (int mt = 0; mt < 4; ++mt)
#pragma unroll
        for (int nt = 0; nt < 4; ++nt) {
            int n = wn + nt * 16 + l15;
#pragma unroll
            for (int r = 0; r < 4; ++r) {
                int m = by * 128 + wm + mt * 16 + quad * 4 + r;
                int b = m >> 11, s = m & 2047;
                if (bx == 0)
                    kc_ws[(((size_t)b * H_ + h) * S_ + s) * DK_ + n] = (bf16)acc[mt][nt][r];
                else
                    vt_ws[(((size_t)b * H_ + h) * DV_ + n) * S_ + s] = (bf16)acc[mt][nt][r];
            }
        }
}

// ----------------------------------------------------------------------------
// Flash-style causal attention (MFMA). Block = 64 q rows x 4 waves.
// OUTPUT IS FLOAT32. grid (32, 32)
// ----------------------------------------------------------------------------
#define KSTR 200
#define VSTR 72
#define PSTR 72

__global__ __launch_bounds__(256, 2) void k_attn(
    const bf16* __restrict__ q_ws, const bf16* __restrict__ kc_ws,
    const bf16* __restrict__ kr_ws, const bf16* __restrict__ vt_ws,
    float* __restrict__ out) {
    __shared__ __attribute__((aligned(16))) bf16 K_lds[64 * KSTR];
    __shared__ __attribute__((aligned(16))) bf16 Vt_lds[128 * VSTR];
    __shared__ __attribute__((aligned(16))) bf16 P_lds[4 * 16 * PSTR];
    int qt = 31 - blockIdx.x;       // long blocks first
    int bh = blockIdx.y;
    int b = bh >> 4, h = bh & 15;
    int q0 = qt * 64;
    int tid = threadIdx.x, wave = tid >> 6, lane = tid & 63;
    int l15 = lane & 15, quad = lane >> 4;

    const bf16* qrow = q_ws + ((size_t)bh * S_ + q0 + wave * 16 + l15) * DQK_;
    bfx8 qf[6];
#pragma unroll
    for (int ks = 0; ks < 6; ++ks)
        qf[ks] = *(const bfx8*)(qrow + ks * 32 + quad * 8);

    float m_run[4], l_run[4];
    floatx4 o_acc[8];
#pragma unroll
    for (int r = 0; r < 4; ++r) { m_run[r] = -1e30f; l_run[r] = 0.f; }
#pragma unroll
    for (int vt = 0; vt < 8; ++vt) o_acc[vt] = (floatx4){0.f, 0.f, 0.f, 0.f};

    const float C1 = 0.10411754f;  // (1/sqrt(192)) * log2(e)
    int ntiles = qt + 1;
    for (int t = 0; t < ntiles; ++t) {
        int kv0 = t * 64;
        __syncthreads();
        {
            const bf16* src = kc_ws + ((size_t)bh * S_ + kv0) * DK_;
#pragma unroll
            for (int i = 0; i < 4; ++i) {
                int flat = (i * 256 + tid) * 8;
                int n = flat >> 7, cc = flat & 127;
                *(bfx8*)(&K_lds[n * KSTR + cc]) = *(const bfx8*)(src + (size_t)n * DK_ + cc);
            }
            const bf16* srk = kr_ws + ((size_t)b * S_ + kv0) * DR_;
#pragma unroll
            for (int i = 0; i < 2; ++i) {
                int flat = (i * 256 + tid) * 8;
                int n = flat >> 6, cc = flat & 63;
                *(bfx8*)(&K_lds[n * KSTR + 128 + cc]) = *(const bfx8*)(srk + (size_t)n * DR_ + cc);
            }
            const bf16* srv = vt_ws + (size_t)bh * DV_ * S_ + kv0;
#pragma unroll
            for (int i = 0; i < 4; ++i) {
                int flat = (i * 256 + tid) * 8;
                int v = flat >> 6, cc = flat & 63;
                *(bfx8*)(&Vt_lds[v * VSTR + cc]) = *(const bfx8*)(srv + (size_t)v * S_ + cc);
            }
        }
        __syncthreads();

        floatx4 sc[4];
#pragma unroll
        for (int nt = 0; nt < 4; ++nt) sc[nt] = (floatx4){0.f, 0.f, 0.f, 0.f};
#pragma unroll
        for (int ks = 0; ks < 6; ++ks)
#pragma unroll
            for (int nt = 0; nt < 4; ++nt) {
                bfx8 kf = *(const bfx8*)(&K_lds[(nt * 16 + l15) * KSTR + ks * 32 + quad * 8]);
                sc[nt] = __builtin_amdgcn_mfma_f32_16x16x32_bf16(qf[ks], kf, sc[nt], 0, 0, 0);
            }
        if (t == ntiles - 1) {
#pragma unroll
            for (int nt = 0; nt < 4; ++nt)
#pragma unroll
                for (int r = 0; r < 4; ++r) {
                    int n_g = kv0 + nt * 16 + l15;
                    int q_g = q0 + wave * 16 + quad * 4 + r;
                    if (n_g > q_g) sc[nt][r] = MASK_VAL;
                }
        }
        float pm[4][4];
#pragma unroll
        for (int r = 0; r < 4; ++r) {
            float mx = fmaxf(fmaxf(sc[0][r], sc[1][r]), fmaxf(sc[2][r], sc[3][r]));
            mx = fmaxf(mx, __shfl_xor(mx, 1));
            mx = fmaxf(mx, __shfl_xor(mx, 2));
            mx = fmaxf(mx, __shfl_xor(mx, 4));
            mx = fmaxf(mx, __shfl_xor(mx, 8));
            float mnew = fmaxf(m_run[r], mx * C1);
            float alpha = exp2f(m_run[r] - mnew);
            m_run[r] = mnew;
            float rs = 0.f;
#pragma unroll
            for (int nt = 0; nt < 4; ++nt) {
                float p = exp2f(sc[nt][r] * C1 - mnew);
                pm[nt][r] = p;
                rs += p;
            }
            rs += __shfl_xor(rs, 1);
            rs += __shfl_xor(rs, 2);
            rs += __shfl_xor(rs, 4);
            rs += __shfl_xor(rs, 8);
            l_run[r] = l_run[r] * alpha + rs;
#pragma unroll
            for (int vt = 0; vt < 8; ++vt) o_acc[vt][r] = o_acc[vt][r] * alpha;
        }
#pragma unroll
        for (int nt = 0; nt < 4; ++nt)
#pragma unroll
            for (int r = 0; r < 4; ++r)
                P_lds[(wave * 16 + quad * 4 + r) * PSTR + nt * 16 + l15] = (bf16)pm[nt][r];
        __syncthreads();
#pragma unroll
        for (int ks2 = 0; ks2 < 2; ++ks2) {
            bfx8 pf = *(const bfx8*)(&P_lds[(wave * 16 + l15) * PSTR + ks2 * 32 + quad * 8]);
#pragma unroll
            for (int vt = 0; vt < 8; ++vt) {
                bfx8 vf = *(const bfx8*)(&Vt_lds[(vt * 16 + l15) * VSTR + ks2 * 32 + quad * 8]);
                o_acc[vt] = __builtin_amdgcn_mfma_f32_16x16x32_bf16(pf, vf, o_acc[vt], 0, 0, 0);
            }
        }
    }
    // epilogue: normalize + store FLOAT32 out[b][s][h*128+v]
    float rinv[4];
#pragma unroll
    for (int r = 0; r < 4; ++r) rinv[r] = 1.f / l_run[r];
#pragma unroll
    for (int vt = 0; vt < 8; ++vt)
#pragma unroll
        for (int r = 0; r < 4; ++r) {
            int s = q0 + wave * 16 + quad * 4 + r;
            int v = vt * 16 + l15;
            out[((size_t)b * S_ + s) * (H_ * DV_) + h * DV_ + v] = o_acc[vt][r] * rinv[r];
        }
}

// ----------------------------------------------------------------------------
extern "C" void kernel_launch(void* const* d_in, const int* in_sizes, int n_in,
                              void* d_out, int out_size, void* d_ws, size_t ws_size,
                              hipStream_t stream) {
    // Inputs f32; OUTPUT f32 (reference preserves float32).
    const float* x    = (const float*)d_in[0];
    const float* W_c  = (const float*)d_in[1];
    const float* W_cp = (const float*)d_in[2];
    const float* W_qc = (const float*)d_in[3];
    const float* W_qr = (const float*)d_in[4];
    const float* W_kc = (const float*)d_in[5];
    const float* W_kr = (const float*)d_in[6];
    const float* W_v  = (const float*)d_in[7];
    float* out = (float*)d_out;

    // c/cp (12 MB bf16) live only between G1 and G3/G2; host in d_out
    // (33.5 MB f32), fully overwritten by k_attn afterwards.
    bf16* c_ws  = (bf16*)d_out;
    bf16* cp_ws = (bf16*)d_out + (size_t)B_ * S_ * DC_;

    char* ws = (char*)d_ws;
    size_t off = 0;
    auto alloc = [&](size_t elems) { bf16* p = (bf16*)(ws + off); off += elems * sizeof(bf16); return p; };
    bf16* Wt_c  = alloc((size_t)DIM_ * DC_);
    bf16* Wt_cp = alloc((size_t)DIM_ * DCP_);
    bf16* Wt_qc = alloc((size_t)H_ * DCP_ * DK_);
    bf16* Wt_qr = alloc((size_t)H_ * DCP_ * DR_);
    bf16* Wt_kc = alloc((size_t)H_ * DC_ * DK_);
    bf16* Wt_kr = alloc((size_t)DIM_ * DR_);
    bf16* Wt_v  = alloc((size_t)H_ * DC_ * DV_);
    bf16* kr_ws = alloc((size_t)B_ * S_ * DR_);
    bf16* q_ws  = alloc((size_t)B_ * H_ * S_ * DQK_);
    bf16* kc_ws = alloc((size_t)B_ * H_ * S_ * DK_);
    bf16* vt_ws = alloc((size_t)B_ * H_ * DV_ * S_);

    k_transpose<<<dim3(DC_ / 32, DIM_ / 32, 1),  256, 0, stream>>>(W_c,  Wt_c,  DIM_, DC_);
    k_transpose<<<dim3(DCP_ / 32, DIM_ / 32, 1), 256, 0, stream>>>(W_cp, Wt_cp, DIM_, DCP_);
    k_transpose<<<dim3(DK_ / 32, DCP_ / 32, H_), 256, 0, stream>>>(W_qc, Wt_qc, DCP_, DK_);
    k_transpose<<<dim3(DR_ / 32, DCP_ / 32, H_), 256, 0, stream>>>(W_qr, Wt_qr, DCP_, DR_);
    k_transpose<<<dim3(DK_ / 32, DC_ / 32, H_),  256, 0, stream>>>(W_kc, Wt_kc, DC_, DK_);
    k_transpose<<<dim3(DR_ / 32, DIM_ / 32, 1),  256, 0, stream>>>(W_kr, Wt_kr, DIM_, DR_);
    k_transpose<<<dim3(DV_ / 32, DC_ / 32, H_),  256, 0, stream>>>(W_v,  Wt_v,  DC_, DV_);

    k_gemm1<<<dim3(13, 32), 256, 0, stream>>>(x, Wt_c, Wt_cp, Wt_kr, c_ws, cp_ws, kr_ws);
    k_gemm2<<<dim3(2, 32, H_), 256, 0, stream>>>(cp_ws, Wt_qc, Wt_qr, q_ws);
    k_gemm3<<<dim3(2, 32, H_), 256, 0, stream>>>(c_ws, Wt_kc, Wt_v, kc_ws, vt_ws);
    k_attn<<<dim3(32, B_ * H_), 256, 0, stream>>>(q_ws, kc_ws, kr_ws, vt_ws, out);
}